// Round 9
// baseline (165.326 us; speedup 1.0000x reference)
//
#include <hip/hip_runtime.h>
#include <math.h>

typedef _Float16 f16;
typedef __attribute__((ext_vector_type(4))) _Float16 f16x4;
typedef __attribute__((ext_vector_type(8))) _Float16 f16x8;
typedef __attribute__((ext_vector_type(4))) float f32x4;
typedef __attribute__((ext_vector_type(16))) float f32x16;

#define NB 2
#define NH 16
#define TQ 1024
#define TK 2048
#define DM 1536
#define HD 96
#define RH 48

__device__ __forceinline__ f32x4 mfma16(f16x8 a, f16x8 b, f32x4 c) {
    return __builtin_amdgcn_mfma_f32_16x16x32_f16(a, b, c, 0, 0, 0);
}

#define GLDS16(gptr, lptr) __builtin_amdgcn_global_load_lds( \
    (const __attribute__((address_space(1))) unsigned int*)(gptr), \
    (__attribute__((address_space(3))) unsigned int*)(lptr), 16, 0, 0)

// ---------------- conversions (fused launches) ----------------
__global__ void cvt_w4(const float4* __restrict__ W0, const float4* __restrict__ W1,
                       const float4* __restrict__ W2, const float4* __restrict__ W3,
                       f16x4* __restrict__ o0, f16x4* __restrict__ o1,
                       f16x4* __restrict__ o2, f16x4* __restrict__ o3, int n4) {
    int i = blockIdx.x * 256 + threadIdx.x;
    if (i >= n4) return;
    const float4* in = blockIdx.y == 0 ? W0 : blockIdx.y == 1 ? W1 : blockIdx.y == 2 ? W2 : W3;
    f16x4* out      = blockIdx.y == 0 ? o0 : blockIdx.y == 1 ? o1 : blockIdx.y == 2 ? o2 : o3;
    float4 v = in[i];
    f16x4 o;
    o[0] = (f16)v.x; o[1] = (f16)v.y; o[2] = (f16)v.z; o[3] = (f16)v.w;
    out[i] = o;
}

__global__ void cvt_xm(const float4* __restrict__ X, const float4* __restrict__ M,
                       f16x4* __restrict__ ox, f16x4* __restrict__ om, int nx4, int nm4) {
    int i = blockIdx.x * 256 + threadIdx.x;
    int n = blockIdx.y == 0 ? nx4 : nm4;
    if (i >= n) return;
    const float4* in = blockIdx.y == 0 ? X : M;
    f16x4* out = blockIdx.y == 0 ? ox : om;
    float4 v = in[i];
    f16x4 o;
    o[0] = (f16)v.x; o[1] = (f16)v.y; o[2] = (f16)v.z; o[3] = (f16)v.w;
    out[i] = o;
}

// ---------------- RoPE sin/cos tables: [B*T][48] ----------------
__global__ void rope_tab2(const float* __restrict__ cq, const float* __restrict__ cm,
                          float* __restrict__ sq, float* __restrict__ cqo,
                          float* __restrict__ sk, float* __restrict__ cko,
                          int nq, int nk) {
    int i = blockIdx.x * 256 + threadIdx.x;
    int n = blockIdx.y == 0 ? nq : nk;
    if (i >= n) return;
    const float* coords = blockIdx.y == 0 ? cq : cm;
    float* sinT = blockIdx.y == 0 ? sq : sk;
    float* cosT = blockIdx.y == 0 ? cqo : cko;
    int bt = i / 48, idx = i - bt * 48;
    int axis = idx >> 4, f = idx & 15;
    float inv = powf(10000.f, -(float)f * (1.f / 16.f));
    float ang = coords[bt * 3 + axis] * inv;
    sinT[i] = sinf(ang);
    cosT[i] = cosf(ang);
}

// ---------------- RoPE rotation in-place on [B,H,T,stride] f16 ----------------
__global__ void rope_apply_k(f16* __restrict__ qk, const float* __restrict__ sinT,
                             const float* __restrict__ cosT, int T, int stride,
                             float scale, int n) {
    int i = blockIdx.x * 256 + threadIdx.x;
    if (i >= n) return;
    int p = i % 48;
    int rest = i / 48;              // (b*NH + h)*T + t
    int t = rest % T;
    int b = rest / (NH * T);
    long base = (long)rest * stride;
    float x1 = (float)qk[base + p];
    float x2 = (float)qk[base + p + RH];
    int ti = (b * T + t) * 48 + p;
    float s = sinT[ti], c = cosT[ti];
    qk[base + p]      = (f16)((x1 * c - x2 * s) * scale);
    qk[base + p + RH] = (f16)((x2 * c + x1 * s) * scale);
}

// ---------------- GEMM v6: 32x32x16 MFMA + register-pipelined k-steps ----------------
// CFG 0: fused QKV. BM=BN=256, 512 thr (8 waves 2Mx4N, wave tile 128x64 = 4x2 of 32x32).
// CFG 1: O-proj. BM=BN=128, 256 thr (4 waves 2x2, wave tile 64x64 = 2x2 of 32x32).
// Per K-tile (BK=64, 4 k-steps of K=16):
//   STG(t+1) 8 gloads; vmcnt(8); barrier_A;
//   read ks0; read ks1; MFMA ks0; read ks2; MFMA ks1; read ks3; MFMA ks2;
//   lgkmcnt(0); barrier_B; MFMA ks3 (regs only, overlaps next STG issue).
// Frag reads run ahead of MFMAs -> LDS pipe overlaps matrix pipe (fixes r7/r8's
// burst alternation). 2 LDS buffers; race-audited: all reads of buf drained
// (lgkmcnt 0) before barrier_B; STG of same buf only issued after barrier_B.
// 32x32 C layout: col = lane&31, row = (r&3)+8*(r>>2)+4*(lane>>5)  [m74/m101].
template <int CFG>
__global__ __launch_bounds__(CFG == 0 ? 512 : 256, 2)
void gemmP(const f16* __restrict__ Aq, const f16* __restrict__ Akv,
           const f16* __restrict__ Wqp, const f16* __restrict__ Wkp, const f16* __restrict__ Wvp,
           const float* __restrict__ bqp, const float* __restrict__ bkp, const float* __restrict__ bvp,
           f16* __restrict__ outq, f16* __restrict__ outk, f16* __restrict__ outv,
           float* __restrict__ outo) {
    constexpr int BMx = CFG == 0 ? 256 : 128;
    constexpr int BNx = CFG == 0 ? 256 : 128;
    constexpr int TPB = CFG == 0 ? 512 : 256;
    constexpr int MT  = CFG == 0 ? 4 : 2;     // 32-row m-tiles per wave
    constexpr int ABUF = BMx * 64;            // f16 per A region
    constexpr int BUFSZ = (BMx + BNx) * 64;   // f16 per buffer
    constexpr int NT = DM / 64;               // 24 K-tiles

    __shared__ f16 Buf[2][BUFSZ];

    const int tid = threadIdx.x, w = tid >> 6, lane = tid & 63;
    const int q31 = lane & 31, hf = lane >> 5;

    int sel = 0, mt, nt;
    const f16* A; const f16* W; const float* bias;
    if constexpr (CFG == 0) {
        const int bid = blockIdx.x;
        const int wid = (bid & 7) * 30 + (bid >> 3);   // bijective (240 = 8*30)
        if (wid < 48)       { sel = 0; mt = wid / 6;        nt = wid - mt * 6;        A = Aq;  W = Wqp; bias = bqp; }
        else if (wid < 144) { sel = 1; int r = wid - 48;  mt = r / 6; nt = r - mt * 6; A = Akv; W = Wkp; bias = bkp; }
        else                { sel = 2; int r = wid - 144; mt = r / 6; nt = r - mt * 6; A = Akv; W = Wvp; bias = bvp; }
    } else {
        const int bid = blockIdx.x;
        const int wid = (bid & 7) * 24 + (bid >> 3);   // bijective (192 = 8*24)
        mt = wid / 12; nt = wid - mt * 12;
        A = Aq; W = Wqp; bias = bqp;
    }
    const int m0 = mt * BMx, n0 = nt * BNx;
    const int wm = (w & 1) * (MT * 32);
    const int wn = (w >> 1) * 64;

    // pre-swizzled per-lane global source offsets (f16 units); 4 rounds each A/B
    int src[4];
#pragma unroll
    for (int r = 0; r < 4; r++) {
        int L = r * (TPB * 16) + tid * 16;   // linear LDS byte offset within region
        int row = L >> 7, seg = (L >> 4) & 7;
        src[r] = row * DM + ((seg ^ (row & 7)) << 3);
    }
    const f16* Ag = A + (long)m0 * DM;
    const f16* Bg = W + (long)n0 * DM;

    // fragment LDS element offsets: row = tile_row + q31; f16 off = ks*16 + hf*8
    int aoff[MT][4], boff[2][4];
#pragma unroll
    for (int i = 0; i < MT; i++) {
        int row = wm + i * 32 + q31;
#pragma unroll
        for (int ks = 0; ks < 4; ks++)
            aoff[i][ks] = row * 64 + (((ks * 2 + hf) ^ (row & 7)) << 3);
    }
#pragma unroll
    for (int j = 0; j < 2; j++) {
        int row = wn + j * 32 + q31;
#pragma unroll
        for (int ks = 0; ks < 4; ks++)
            boff[j][ks] = ABUF + row * 64 + (((ks * 2 + hf) ^ (row & 7)) << 3);
    }

#define STG(bufp, kt) do { \
    _Pragma("unroll") for (int r_ = 0; r_ < 4; r_++) { \
        GLDS16(Ag + src[r_] + (kt) * 64, &Buf[bufp][r_ * (TPB * 8) + w * 512]); \
        GLDS16(Bg + src[r_] + (kt) * 64, &Buf[bufp][ABUF + r_ * (TPB * 8) + w * 512]); \
    } \
} while (0)

#define RD(aset, bset, ks) do { \
    _Pragma("unroll") for (int i_ = 0; i_ < MT; i_++) \
        aset[i_] = *(const f16x8*)&bp[aoff[i_][ks]]; \
    _Pragma("unroll") for (int j_ = 0; j_ < 2; j_++) \
        bset[j_] = *(const f16x8*)&bp[boff[j_][ks]]; \
} while (0)

#define MM(aset, bset) do { \
    __builtin_amdgcn_s_setprio(1); \
    _Pragma("unroll") for (int i_ = 0; i_ < MT; i_++) \
        _Pragma("unroll") for (int j_ = 0; j_ < 2; j_++) \
            acc[i_][j_] = __builtin_amdgcn_mfma_f32_32x32x16_f16(aset[i_], bset[j_], acc[i_][j_], 0, 0, 0); \
    __builtin_amdgcn_s_setprio(0); \
} while (0)

    f32x16 acc[MT][2] = {};

    STG(0, 0);
#pragma unroll 1
    for (int t = 0; t < NT; ++t) {
        const int bi = t & 1;
        if (t + 1 < NT) {
            STG(bi ^ 1, t + 1);
            asm volatile("s_waitcnt vmcnt(8)" ::: "memory");   // tile t's 8 loads landed
        } else {
            asm volatile("s_waitcnt vmcnt(0)" ::: "memory");
        }
        __builtin_amdgcn_s_barrier();
        __builtin_amdgcn_sched_barrier(0);
        const f16* bp = &Buf[bi][0];

        f16x8 fa0[MT], fb0[2], fa1[MT], fb1[2];
        RD(fa0, fb0, 0);
        RD(fa1, fb1, 1);
        MM(fa0, fb0);            // ks0 (ks1 reads in flight above)
        RD(fa0, fb0, 2);
        MM(fa1, fb1);            // ks1 (ks2 reads in flight)
        RD(fa1, fb1, 3);
        MM(fa0, fb0);            // ks2 (ks3 reads in flight)
        asm volatile("s_waitcnt lgkmcnt(0)" ::: "memory");
        __builtin_amdgcn_sched_barrier(0);
        __builtin_amdgcn_s_barrier();
        MM(fa1, fb1);            // ks3: regs only — overlaps next tile's STG issue
    }
#undef STG
#undef RD
#undef MM

    // ---- epilogue (32x32 C layout) ----
#pragma unroll
    for (int i = 0; i < MT; i++) {
#pragma unroll
        for (int j = 0; j < 2; j++) {
            const int n = n0 + wn + j * 32 + q31;
            const float bn = bias[n];
            if constexpr (CFG == 1) {
#pragma unroll
                for (int r = 0; r < 16; r++) {
                    int m = m0 + wm + i * 32 + (r & 3) + 8 * (r >> 2) + 4 * hf;
                    outo[(long)m * DM + n] = acc[i][j][r] + bn;
                }
            } else {
                const int hh = n / HD, hd = n - hh * HD;
                if (sel == 0) {            // Q [B,H,TQ,96]
#pragma unroll
                    for (int r = 0; r < 16; r++) {
                        int m = m0 + wm + i * 32 + (r & 3) + 8 * (r >> 2) + 4 * hf;
                        int bq = m >> 10, t = m & (TQ - 1);
                        outq[(((long)bq * NH + hh) * TQ + t) * 96 + hd] = (f16)(acc[i][j][r] + bn);
                    }
                } else if (sel == 1) {     // K padded [B,H,TK,128]
#pragma unroll
                    for (int r = 0; r < 16; r++) {
                        int m = m0 + wm + i * 32 + (r & 3) + 8 * (r >> 2) + 4 * hf;
                        int bq = m >> 11, t = m & (TK - 1);
                        outk[(((long)bq * NH + hh) * TK + t) * 128 + hd] = (f16)(acc[i][j][r] + bn);
                    }
                } else {                   // V^T [B,H,96,TK]: regs 4g..4g+3 = 4 consecutive t
#pragma unroll
                    for (int g = 0; g < 4; g++) {
                        int mb = m0 + wm + i * 32 + 8 * g + 4 * hf;
                        int bq = mb >> 11, t = mb & (TK - 1);
                        f16x4 pk;
#pragma unroll
                        for (int e = 0; e < 4; e++) pk[e] = (f16)(acc[i][j][4 * g + e] + bn);
                        *(f16x4*)&outv[(((long)bq * NH + hh) * HD + hd) * TK + t] = pk;
                    }
                }
            }
        }
    }
}

// ---------------- Flash attention (round-3 structure, unchanged) ----------------
__global__ __launch_bounds__(256, 2) void attn_fwd(
    const f16* __restrict__ Q, const f16* __restrict__ Kg,
    const f16* __restrict__ Vg, f16* __restrict__ O) {
    __shared__ f16 Kl[2][64 * 128];
    __shared__ f16 Vl[2][96 * 64];
    __shared__ f16 Pl[4][32 * 64];

    const int tid = threadIdx.x, w = tid >> 6, lane = tid & 63;
    const int q31 = lane & 31, hf = lane >> 5;
    const int half = w >> 1, u = w & 1;

    const int linear = blockIdx.x + (int)(gridDim.x * (blockIdx.y + gridDim.y * blockIdx.z));
    const int wid = (linear & 7) * 64 + (linear >> 3);
    const int qc = wid & 15, h = (wid >> 4) & 15, b = wid >> 8;

    const long kbase = (long)(b * NH + h) * TK * 128;
    const long vbase = (long)(b * NH + h) * HD * TK;
    const long qbase = (long)(b * NH + h) * TQ * 96;
    const int q0 = qc * 64 + u * 32;

    int ksrc[8], vsrc[6];
#pragma unroll
    for (int i = 0; i < 8; i++) {
        int L = (u * 8 + i) * 1024 + lane * 16;
        int r = L >> 8, s = (L >> 4) & 15;
        ksrc[i] = r * 128 + ((s ^ (r & 7)) << 3);
    }
#pragma unroll
    for (int i = 0; i < 6; i++) {
        int L = (u * 6 + i) * 1024 + lane * 16;
        int r = L >> 7, s = (L >> 4) & 7;
        vsrc[i] = r * TK + ((s ^ (r & 7)) << 3);
    }

    f16x8 qf[6];
#pragma unroll
    for (int s = 0; s < 6; s++)
        qf[s] = *(const f16x8*)&Q[qbase + (long)(q0 + q31) * 96 + hf * 8 + 16 * s];

    float mx = -3e38f, ls = 0.f;
    f32x16 acc[3] = {};

#define STAGE(c_) do { \
    const f16* kp_ = Kg + kbase + (long)(half * 16 + (c_)) * (64 * 128); \
    _Pragma("unroll") for (int i_ = 0; i_ < 8; i_++) \
        GLDS16(kp_ + ksrc[i_], &Kl[half][(u * 8 + i_) * 512]); \
    const f16* vp_ = Vg + vbase + (half * 16 + (c_)) * 64; \
    _Pragma("unroll") for (int i_ = 0; i_ < 6; i_++) \
        GLDS16(vp_ + vsrc[i_], &Vl[half][(u * 6 + i_) * 512]); \
} while (0)

    STAGE(0);

    for (int c = 0; c < 16; ++c) {
        __syncthreads();

        f32x16 st[2] = {};
#pragma unroll
        for (int kt = 0; kt < 2; kt++)
#pragma unroll
            for (int s = 0; s < 6; s++) {
                f16x8 kf = *(const f16x8*)&Kl[half][(kt * 32 + q31) * 128 +
                                                    (((hf + 2 * s) ^ (q31 & 7)) << 3)];
                st[kt] = __builtin_amdgcn_mfma_f32_32x32x16_f16(kf, qf[s], st[kt], 0, 0, 0);
            }

        float t16[16];
#pragma unroll
        for (int r = 0; r < 16; r++) t16[r] = fmaxf(st[0][r], st[1][r]);
#pragma unroll
        for (int o = 8; o >= 1; o >>= 1)
#pragma unroll
            for (int r = 0; r < o; r++) t16[r] = fmaxf(t16[r], t16[r + o]);
        float cm = fmaxf(t16[0], __shfl_xor(t16[0], 32));
        float mn = fmaxf(mx, cm);
        float corr = exp2f(mx - mn);
        mx = mn;
#pragma unroll
        for (int kt = 0; kt < 2; kt++)
#pragma unroll
            for (int r = 0; r < 16; r++) st[kt][r] = exp2f(st[kt][r] - mn);
        float s16[16];
#pragma unroll
        for (int r = 0; r < 16; r++) s16[r] = st[0][r] + st[1][r];
#pragma unroll
        for (int o = 8; o >= 1; o >>= 1)
#pragma unroll
            for (int r = 0; r < o; r++) s16[r] += s16[r + o];
        ls = ls * corr + s16[0];
#pragma unroll
        for (int dt = 0; dt < 3; dt++)
#pragma unroll
            for (int r = 0; r < 16; r++) acc[dt][r] *= corr;

#pragma unroll
        for (int kt = 0; kt < 2; kt++)
#pragma unroll
            for (int jq = 0; jq < 4; jq++) {
                f16x4 pk;
#pragma unroll
                for (int e = 0; e < 4; e++) pk[e] = (f16)st[kt][jq * 4 + e];
                int seg = kt * 4 + jq;
                *(f16x4*)&Pl[w][q31 * 64 + ((seg ^ (q31 & 7)) << 3) + hf * 4] = pk;
            }

#pragma unroll
        for (int ks = 0; ks < 4; ks++) {
            f16x8 pf = *(const f16x8*)&Pl[w][q31 * 64 + (((hf + 2 * ks) ^ (q31 & 7)) << 3)];
#pragma unroll
            for (int dt = 0; dt < 3; dt++) {
                f16x8 vf = *(const f16x8*)&Vl[half][(dt * 32 + q31) * 64 +
                                                    (((hf + 2 * ks) ^ (q31 & 7)) << 3)];
                acc[dt] = __builtin_amdgcn_mfma_f32_32x32x16_f16(vf, pf, acc[dt], 0, 0, 0);
            }
        }

        __syncthreads();
        if (c < 15) STAGE(c + 1);
    }

    ls += __shfl_xor(ls, 32);
    float* dump = (float*)&Kl[0][0] + u * (64 * 52);
    __syncthreads();
    if (half == 1) {
        float* dl = dump + lane * 52;
        dl[0] = mx; dl[1] = ls;
#pragma unroll
        for (int dt = 0; dt < 3; dt++)
#pragma unroll
            for (int r = 0; r < 16; r++) dl[2 + dt * 16 + r] = acc[dt][r];
    }
    __syncthreads();
    if (half == 0) {
        const float* dl = dump + lane * 52;
        float mb = dl[0], lsb = dl[1];
        float mf = fmaxf(mx, mb);
        float ca = exp2f(mx - mf), cb = exp2f(mb - mf);
        float inv = 1.f / (ls * ca + lsb * cb);
        const long orow = (long)(b * TQ + q0 + q31) * DM + h * 96;
#pragma unroll
        for (int dt = 0; dt < 3; dt++)
#pragma unroll
            for (int jq = 0; jq < 4; jq++) {
                f16x4 ov;
#pragma unroll
                for (int e = 0; e < 4; e++) {
                    int r = jq * 4 + e;
                    ov[e] = (f16)((acc[dt][r] * ca + dl[2 + dt * 16 + r] * cb) * inv);
                }
                *(f16x4*)&O[orow + dt * 32 + jq * 8 + hf * 4] = ov;
            }
    }
}

// ---------------- host ----------------
extern "C" void kernel_launch(void* const* d_in, const int* in_sizes, int n_in,
                              void* d_out, int out_size, void* d_ws, size_t ws_size,
                              hipStream_t stream) {
    const float* x   = (const float*)d_in[0];
    const float* mem = (const float*)d_in[1];
    const float* qc  = (const float*)d_in[2];
    const float* mc  = (const float*)d_in[3];
    const float* Wq  = (const float*)d_in[4];
    const float* bq  = (const float*)d_in[5];
    const float* Wk  = (const float*)d_in[6];
    const float* bk  = (const float*)d_in[7];
    const float* Wv  = (const float*)d_in[8];
    const float* bv  = (const float*)d_in[9];
    const float* Wo  = (const float*)d_in[10];
    const float* bo  = (const float*)d_in[11];
    float* out = (float*)d_out;

    const long nx  = (long)NB * TQ * DM;
    const long nm  = (long)NB * TK * DM;
    const long nw  = (long)DM * DM;
    const long nq  = (long)NB * NH * TQ * 96;
    const long nkp = (long)NB * NH * TK * 128;
    const long nvt = (long)NB * NH * HD * TK;

    char* ws = (char*)d_ws;
    size_t off = 0;
    auto alloc = [&](size_t bytes) { size_t o = off; off = (off + bytes + 255) & ~(size_t)255; return o; };
    f16* x16   = (f16*)(ws + alloc(nx * 2));     // reused as at16 after Q-proj
    f16* mem16 = (f16*)(ws + alloc(nm * 2));
    f16* wq16  = (f16*)(ws + alloc(nw * 2));
    f16* wk16  = (f16*)(ws + alloc(nw * 2));
    f16* wv16  = (f16*)(ws + alloc(nw * 2));
    f16* wo16  = (f16*)(ws + alloc(nw * 2));
    f16* q16   = (f16*)(ws + alloc(nq * 2));
    f16* k16p  = (f16*)(ws + alloc(nkp * 2));
    f16* vt16  = (f16*)(ws + alloc(nvt * 2));
    float* sinq = (float*)(ws + alloc((size_t)NB * TQ * 48 * 4));
    float* cosq = (float*)(ws + alloc((size_t)NB * TQ * 48 * 4));
    float* sink = (float*)(ws + alloc((size_t)NB * TK * 48 * 4));
    float* cosk = (float*)(ws + alloc((size_t)NB * TK * 48 * 4));
    f16* at16 = x16;

    cvt_w4<<<dim3((int)(nw / 4 / 256), 4), 256, 0, stream>>>(
        (const float4*)Wq, (const float4*)Wk, (const float4*)Wv, (const float4*)Wo,
        (f16x4*)wq16, (f16x4*)wk16, (f16x4*)wv16, (f16x4*)wo16, (int)(nw / 4));
    cvt_xm<<<dim3((int)(nm / 4 / 256), 2), 256, 0, stream>>>(
        (const float4*)x, (const float4*)mem, (f16x4*)x16, (f16x4*)mem16,
        (int)(nx / 4), (int)(nm / 4));

    rope_tab2<<<dim3((NB * TK * 48 + 255) / 256, 2), 256, 0, stream>>>(
        qc, mc, sinq, cosq, sink, cosk, NB * TQ * 48, NB * TK * 48);

    // fused QKV projection: 240 blocks (48 Q + 96 K + 96 V), one dispatch round
    gemmP<0><<<240, 512, 0, stream>>>(
        x16, mem16, wq16, wk16, wv16, bq, bk, bv, q16, k16p, vt16, nullptr);

    const float qscale = 0.10206207261596577f * 1.4426950408889634f;  // 1/sqrt(96)*log2(e)
    rope_apply_k<<<(NB * NH * TQ * 48 + 255) / 256, 256, 0, stream>>>(
        q16, sinq, cosq, TQ, 96, qscale, NB * NH * TQ * 48);
    rope_apply_k<<<(NB * NH * TK * 48 + 255) / 256, 256, 0, stream>>>(
        k16p, sink, cosk, TK, 128, 1.0f, NB * NH * TK * 48);

    attn_fwd<<<dim3(16, 16, 2), 256, 0, stream>>>(q16, k16p, vt16, at16);

    // output projection -> f32 (128x128 tiles, 192 blocks, 2 blocks/CU)
    gemmP<1><<<192, 256, 0, stream>>>(
        at16, nullptr, wo16, nullptr, nullptr, bo, nullptr, nullptr,
        nullptr, nullptr, nullptr, out);
}

// Round 10
// 164.446 us; speedup vs baseline: 1.0053x; 1.0053x over previous
//
#include <hip/hip_runtime.h>
#include <math.h>

typedef _Float16 f16;
typedef __attribute__((ext_vector_type(4))) _Float16 f16x4;
typedef __attribute__((ext_vector_type(8))) _Float16 f16x8;
typedef __attribute__((ext_vector_type(4))) float f32x4;
typedef __attribute__((ext_vector_type(16))) float f32x16;

#define NB 2
#define NH 16
#define TQ 1024
#define TK 2048
#define DM 1536
#define HD 96
#define RH 48

__device__ __forceinline__ f32x4 mfma16(f16x8 a, f16x8 b, f32x4 c) {
    return __builtin_amdgcn_mfma_f32_16x16x32_f16(a, b, c, 0, 0, 0);
}

#define GLDS16(gptr, lptr) __builtin_amdgcn_global_load_lds( \
    (const __attribute__((address_space(1))) unsigned int*)(gptr), \
    (__attribute__((address_space(3))) unsigned int*)(lptr), 16, 0, 0)

// ---------------- conversions (fused launches) ----------------
__global__ void cvt_w4(const float4* __restrict__ W0, const float4* __restrict__ W1,
                       const float4* __restrict__ W2, const float4* __restrict__ W3,
                       f16x4* __restrict__ o0, f16x4* __restrict__ o1,
                       f16x4* __restrict__ o2, f16x4* __restrict__ o3, int n4) {
    int i = blockIdx.x * 256 + threadIdx.x;
    if (i >= n4) return;
    const float4* in = blockIdx.y == 0 ? W0 : blockIdx.y == 1 ? W1 : blockIdx.y == 2 ? W2 : W3;
    f16x4* out      = blockIdx.y == 0 ? o0 : blockIdx.y == 1 ? o1 : blockIdx.y == 2 ? o2 : o3;
    float4 v = in[i];
    f16x4 o;
    o[0] = (f16)v.x; o[1] = (f16)v.y; o[2] = (f16)v.z; o[3] = (f16)v.w;
    out[i] = o;
}

__global__ void cvt_xm(const float4* __restrict__ X, const float4* __restrict__ M,
                       f16x4* __restrict__ ox, f16x4* __restrict__ om, int nx4, int nm4) {
    int i = blockIdx.x * 256 + threadIdx.x;
    int n = blockIdx.y == 0 ? nx4 : nm4;
    if (i >= n) return;
    const float4* in = blockIdx.y == 0 ? X : M;
    f16x4* out = blockIdx.y == 0 ? ox : om;
    float4 v = in[i];
    f16x4 o;
    o[0] = (f16)v.x; o[1] = (f16)v.y; o[2] = (f16)v.z; o[3] = (f16)v.w;
    out[i] = o;
}

// ---------------- RoPE sin/cos tables: [B*T][48] ----------------
__global__ void rope_tab2(const float* __restrict__ cq, const float* __restrict__ cm,
                          float* __restrict__ sq, float* __restrict__ cqo,
                          float* __restrict__ sk, float* __restrict__ cko,
                          int nq, int nk) {
    int i = blockIdx.x * 256 + threadIdx.x;
    int n = blockIdx.y == 0 ? nq : nk;
    if (i >= n) return;
    const float* coords = blockIdx.y == 0 ? cq : cm;
    float* sinT = blockIdx.y == 0 ? sq : sk;
    float* cosT = blockIdx.y == 0 ? cqo : cko;
    int bt = i / 48, idx = i - bt * 48;
    int axis = idx >> 4, f = idx & 15;
    float inv = powf(10000.f, -(float)f * (1.f / 16.f));
    float ang = coords[bt * 3 + axis] * inv;
    sinT[i] = sinf(ang);
    cosT[i] = cosf(ang);
}

// ---------------- RoPE rotation in-place on [B,H,T,stride] f16 ----------------
__global__ void rope_apply_k(f16* __restrict__ qk, const float* __restrict__ sinT,
                             const float* __restrict__ cosT, int T, int stride,
                             float scale, int n) {
    int i = blockIdx.x * 256 + threadIdx.x;
    if (i >= n) return;
    int p = i % 48;
    int rest = i / 48;              // (b*NH + h)*T + t
    int t = rest % T;
    int b = rest / (NH * T);
    long base = (long)rest * stride;
    float x1 = (float)qk[base + p];
    float x2 = (float)qk[base + p + RH];
    int ti = (b * T + t) * 48 + p;
    float s = sinT[ti], c = cosT[ti];
    qk[base + p]      = (f16)((x1 * c - x2 * s) * scale);
    qk[base + p + RH] = (f16)((x2 * c + x1 * s) * scale);
}

// ---------------- GEMM v6: 32x32x16 MFMA + register-pipelined k-steps ----------------
// CFG 0: fused QKV. BM=BN=256, 512 thr (8 waves 2Mx4N, wave tile 128x64 = 4x2 of 32x32).
// CFG 1: O-proj. BM=BN=128, 256 thr (4 waves 2x2, wave tile 64x64 = 2x2 of 32x32).
// Per K-tile (BK=64, 4 k-steps of K=16):
//   STG(t+1) 8 gloads; vmcnt(8); barrier_A;
//   read ks0; read ks1; MFMA ks0; read ks2; MFMA ks1; read ks3; MFMA ks2;
//   lgkmcnt(0); barrier_B; MFMA ks3 (regs only, overlaps next STG issue).
// Frag reads run ahead of MFMAs -> LDS pipe overlaps matrix pipe (fixes r7/r8's
// burst alternation). 2 LDS buffers; race-audited: all reads of buf drained
// (lgkmcnt 0) before barrier_B; STG of same buf only issued after barrier_B.
// 32x32 C layout: col = lane&31, row = (r&3)+8*(r>>2)+4*(lane>>5)  [m74/m101].
template <int CFG>
__global__ __launch_bounds__(CFG == 0 ? 512 : 256, 2)
void gemmP(const f16* __restrict__ Aq, const f16* __restrict__ Akv,
           const f16* __restrict__ Wqp, const f16* __restrict__ Wkp, const f16* __restrict__ Wvp,
           const float* __restrict__ bqp, const float* __restrict__ bkp, const float* __restrict__ bvp,
           f16* __restrict__ outq, f16* __restrict__ outk, f16* __restrict__ outv,
           float* __restrict__ outo) {
    constexpr int BMx = CFG == 0 ? 256 : 128;
    constexpr int BNx = CFG == 0 ? 256 : 128;
    constexpr int TPB = CFG == 0 ? 512 : 256;
    constexpr int MT  = CFG == 0 ? 4 : 2;     // 32-row m-tiles per wave
    constexpr int ABUF = BMx * 64;            // f16 per A region
    constexpr int BUFSZ = (BMx + BNx) * 64;   // f16 per buffer
    constexpr int NT = DM / 64;               // 24 K-tiles

    __shared__ f16 Buf[2][BUFSZ];

    const int tid = threadIdx.x, w = tid >> 6, lane = tid & 63;
    const int q31 = lane & 31, hf = lane >> 5;

    int sel = 0, mt, nt;
    const f16* A; const f16* W; const float* bias;
    if constexpr (CFG == 0) {
        const int bid = blockIdx.x;
        const int wid = (bid & 7) * 30 + (bid >> 3);   // bijective (240 = 8*30)
        if (wid < 48)       { sel = 0; mt = wid / 6;        nt = wid - mt * 6;        A = Aq;  W = Wqp; bias = bqp; }
        else if (wid < 144) { sel = 1; int r = wid - 48;  mt = r / 6; nt = r - mt * 6; A = Akv; W = Wkp; bias = bkp; }
        else                { sel = 2; int r = wid - 144; mt = r / 6; nt = r - mt * 6; A = Akv; W = Wvp; bias = bvp; }
    } else {
        const int bid = blockIdx.x;
        const int wid = (bid & 7) * 24 + (bid >> 3);   // bijective (192 = 8*24)
        mt = wid / 12; nt = wid - mt * 12;
        A = Aq; W = Wqp; bias = bqp;
    }
    const int m0 = mt * BMx, n0 = nt * BNx;
    const int wm = (w & 1) * (MT * 32);
    const int wn = (w >> 1) * 64;

    // pre-swizzled per-lane global source offsets (f16 units); 4 rounds each A/B
    int src[4];
#pragma unroll
    for (int r = 0; r < 4; r++) {
        int L = r * (TPB * 16) + tid * 16;   // linear LDS byte offset within region
        int row = L >> 7, seg = (L >> 4) & 7;
        src[r] = row * DM + ((seg ^ (row & 7)) << 3);
    }
    const f16* Ag = A + (long)m0 * DM;
    const f16* Bg = W + (long)n0 * DM;

    // fragment LDS element offsets: row = tile_row + q31; f16 off = ks*16 + hf*8
    int aoff[MT][4], boff[2][4];
#pragma unroll
    for (int i = 0; i < MT; i++) {
        int row = wm + i * 32 + q31;
#pragma unroll
        for (int ks = 0; ks < 4; ks++)
            aoff[i][ks] = row * 64 + (((ks * 2 + hf) ^ (row & 7)) << 3);
    }
#pragma unroll
    for (int j = 0; j < 2; j++) {
        int row = wn + j * 32 + q31;
#pragma unroll
        for (int ks = 0; ks < 4; ks++)
            boff[j][ks] = ABUF + row * 64 + (((ks * 2 + hf) ^ (row & 7)) << 3);
    }

#define STG(bufp, kt) do { \
    _Pragma("unroll") for (int r_ = 0; r_ < 4; r_++) { \
        GLDS16(Ag + src[r_] + (kt) * 64, &Buf[bufp][r_ * (TPB * 8) + w * 512]); \
        GLDS16(Bg + src[r_] + (kt) * 64, &Buf[bufp][ABUF + r_ * (TPB * 8) + w * 512]); \
    } \
} while (0)

#define RD(aset, bset, ks) do { \
    _Pragma("unroll") for (int i_ = 0; i_ < MT; i_++) \
        aset[i_] = *(const f16x8*)&bp[aoff[i_][ks]]; \
    _Pragma("unroll") for (int j_ = 0; j_ < 2; j_++) \
        bset[j_] = *(const f16x8*)&bp[boff[j_][ks]]; \
} while (0)

#define MM(aset, bset) do { \
    __builtin_amdgcn_s_setprio(1); \
    _Pragma("unroll") for (int i_ = 0; i_ < MT; i_++) \
        _Pragma("unroll") for (int j_ = 0; j_ < 2; j_++) \
            acc[i_][j_] = __builtin_amdgcn_mfma_f32_32x32x16_f16(aset[i_], bset[j_], acc[i_][j_], 0, 0, 0); \
    __builtin_amdgcn_s_setprio(0); \
} while (0)

    f32x16 acc[MT][2] = {};

    STG(0, 0);
#pragma unroll 1
    for (int t = 0; t < NT; ++t) {
        const int bi = t & 1;
        if (t + 1 < NT) {
            STG(bi ^ 1, t + 1);
            asm volatile("s_waitcnt vmcnt(8)" ::: "memory");   // tile t's 8 loads landed
        } else {
            asm volatile("s_waitcnt vmcnt(0)" ::: "memory");
        }
        __builtin_amdgcn_s_barrier();
        __builtin_amdgcn_sched_barrier(0);
        const f16* bp = &Buf[bi][0];

        f16x8 fa0[MT], fb0[2], fa1[MT], fb1[2];
        RD(fa0, fb0, 0);
        RD(fa1, fb1, 1);
        MM(fa0, fb0);            // ks0 (ks1 reads in flight above)
        RD(fa0, fb0, 2);
        MM(fa1, fb1);            // ks1 (ks2 reads in flight)
        RD(fa1, fb1, 3);
        MM(fa0, fb0);            // ks2 (ks3 reads in flight)
        asm volatile("s_waitcnt lgkmcnt(0)" ::: "memory");
        __builtin_amdgcn_sched_barrier(0);
        __builtin_amdgcn_s_barrier();
        MM(fa1, fb1);            // ks3: regs only — overlaps next tile's STG issue
    }
#undef STG
#undef RD
#undef MM

    // ---- epilogue (32x32 C layout) ----
#pragma unroll
    for (int i = 0; i < MT; i++) {
#pragma unroll
        for (int j = 0; j < 2; j++) {
            const int n = n0 + wn + j * 32 + q31;
            const float bn = bias[n];
            if constexpr (CFG == 1) {
#pragma unroll
                for (int r = 0; r < 16; r++) {
                    int m = m0 + wm + i * 32 + (r & 3) + 8 * (r >> 2) + 4 * hf;
                    outo[(long)m * DM + n] = acc[i][j][r] + bn;
                }
            } else {
                const int hh = n / HD, hd = n - hh * HD;
                if (sel == 0) {            // Q [B,H,TQ,96]
#pragma unroll
                    for (int r = 0; r < 16; r++) {
                        int m = m0 + wm + i * 32 + (r & 3) + 8 * (r >> 2) + 4 * hf;
                        int bq = m >> 10, t = m & (TQ - 1);
                        outq[(((long)bq * NH + hh) * TQ + t) * 96 + hd] = (f16)(acc[i][j][r] + bn);
                    }
                } else if (sel == 1) {     // K padded [B,H,TK,128]
#pragma unroll
                    for (int r = 0; r < 16; r++) {
                        int m = m0 + wm + i * 32 + (r & 3) + 8 * (r >> 2) + 4 * hf;
                        int bq = m >> 11, t = m & (TK - 1);
                        outk[(((long)bq * NH + hh) * TK + t) * 128 + hd] = (f16)(acc[i][j][r] + bn);
                    }
                } else {                   // V^T [B,H,96,TK]: regs 4g..4g+3 = 4 consecutive t
#pragma unroll
                    for (int g = 0; g < 4; g++) {
                        int mb = m0 + wm + i * 32 + 8 * g + 4 * hf;
                        int bq = mb >> 11, t = mb & (TK - 1);
                        f16x4 pk;
#pragma unroll
                        for (int e = 0; e < 4; e++) pk[e] = (f16)(acc[i][j][4 * g + e] + bn);
                        *(f16x4*)&outv[(((long)bq * NH + hh) * HD + hd) * TK + t] = pk;
                    }
                }
            }
        }
    }
}

// ---------------- Flash attention (round-3 structure, unchanged) ----------------
__global__ __launch_bounds__(256, 2) void attn_fwd(
    const f16* __restrict__ Q, const f16* __restrict__ Kg,
    const f16* __restrict__ Vg, f16* __restrict__ O) {
    __shared__ f16 Kl[2][64 * 128];
    __shared__ f16 Vl[2][96 * 64];
    __shared__ f16 Pl[4][32 * 64];

    const int tid = threadIdx.x, w = tid >> 6, lane = tid & 63;
    const int q31 = lane & 31, hf = lane >> 5;
    const int half = w >> 1, u = w & 1;

    const int linear = blockIdx.x + (int)(gridDim.x * (blockIdx.y + gridDim.y * blockIdx.z));
    const int wid = (linear & 7) * 64 + (linear >> 3);
    const int qc = wid & 15, h = (wid >> 4) & 15, b = wid >> 8;

    const long kbase = (long)(b * NH + h) * TK * 128;
    const long vbase = (long)(b * NH + h) * HD * TK;
    const long qbase = (long)(b * NH + h) * TQ * 96;
    const int q0 = qc * 64 + u * 32;

    int ksrc[8], vsrc[6];
#pragma unroll
    for (int i = 0; i < 8; i++) {
        int L = (u * 8 + i) * 1024 + lane * 16;
        int r = L >> 8, s = (L >> 4) & 15;
        ksrc[i] = r * 128 + ((s ^ (r & 7)) << 3);
    }
#pragma unroll
    for (int i = 0; i < 6; i++) {
        int L = (u * 6 + i) * 1024 + lane * 16;
        int r = L >> 7, s = (L >> 4) & 7;
        vsrc[i] = r * TK + ((s ^ (r & 7)) << 3);
    }

    f16x8 qf[6];
#pragma unroll
    for (int s = 0; s < 6; s++)
        qf[s] = *(const f16x8*)&Q[qbase + (long)(q0 + q31) * 96 + hf * 8 + 16 * s];

    float mx = -3e38f, ls = 0.f;
    f32x16 acc[3] = {};

#define STAGE(c_) do { \
    const f16* kp_ = Kg + kbase + (long)(half * 16 + (c_)) * (64 * 128); \
    _Pragma("unroll") for (int i_ = 0; i_ < 8; i_++) \
        GLDS16(kp_ + ksrc[i_], &Kl[half][(u * 8 + i_) * 512]); \
    const f16* vp_ = Vg + vbase + (half * 16 + (c_)) * 64; \
    _Pragma("unroll") for (int i_ = 0; i_ < 6; i_++) \
        GLDS16(vp_ + vsrc[i_], &Vl[half][(u * 6 + i_) * 512]); \
} while (0)

    STAGE(0);

    for (int c = 0; c < 16; ++c) {
        __syncthreads();

        f32x16 st[2] = {};
#pragma unroll
        for (int kt = 0; kt < 2; kt++)
#pragma unroll
            for (int s = 0; s < 6; s++) {
                f16x8 kf = *(const f16x8*)&Kl[half][(kt * 32 + q31) * 128 +
                                                    (((hf + 2 * s) ^ (q31 & 7)) << 3)];
                st[kt] = __builtin_amdgcn_mfma_f32_32x32x16_f16(kf, qf[s], st[kt], 0, 0, 0);
            }

        float t16[16];
#pragma unroll
        for (int r = 0; r < 16; r++) t16[r] = fmaxf(st[0][r], st[1][r]);
#pragma unroll
        for (int o = 8; o >= 1; o >>= 1)
#pragma unroll
            for (int r = 0; r < o; r++) t16[r] = fmaxf(t16[r], t16[r + o]);
        float cm = fmaxf(t16[0], __shfl_xor(t16[0], 32));
        float mn = fmaxf(mx, cm);
        float corr = exp2f(mx - mn);
        mx = mn;
#pragma unroll
        for (int kt = 0; kt < 2; kt++)
#pragma unroll
            for (int r = 0; r < 16; r++) st[kt][r] = exp2f(st[kt][r] - mn);
        float s16[16];
#pragma unroll
        for (int r = 0; r < 16; r++) s16[r] = st[0][r] + st[1][r];
#pragma unroll
        for (int o = 8; o >= 1; o >>= 1)
#pragma unroll
            for (int r = 0; r < o; r++) s16[r] += s16[r + o];
        ls = ls * corr + s16[0];
#pragma unroll
        for (int dt = 0; dt < 3; dt++)
#pragma unroll
            for (int r = 0; r < 16; r++) acc[dt][r] *= corr;

#pragma unroll
        for (int kt = 0; kt < 2; kt++)
#pragma unroll
            for (int jq = 0; jq < 4; jq++) {
                f16x4 pk;
#pragma unroll
                for (int e = 0; e < 4; e++) pk[e] = (f16)st[kt][jq * 4 + e];
                int seg = kt * 4 + jq;
                *(f16x4*)&Pl[w][q31 * 64 + ((seg ^ (q31 & 7)) << 3) + hf * 4] = pk;
            }

#pragma unroll
        for (int ks = 0; ks < 4; ks++) {
            f16x8 pf = *(const f16x8*)&Pl[w][q31 * 64 + (((hf + 2 * ks) ^ (q31 & 7)) << 3)];
#pragma unroll
            for (int dt = 0; dt < 3; dt++) {
                f16x8 vf = *(const f16x8*)&Vl[half][(dt * 32 + q31) * 64 +
                                                    (((hf + 2 * ks) ^ (q31 & 7)) << 3)];
                acc[dt] = __builtin_amdgcn_mfma_f32_32x32x16_f16(vf, pf, acc[dt], 0, 0, 0);
            }
        }

        __syncthreads();
        if (c < 15) STAGE(c + 1);
    }

    ls += __shfl_xor(ls, 32);
    float* dump = (float*)&Kl[0][0] + u * (64 * 52);
    __syncthreads();
    if (half == 1) {
        float* dl = dump + lane * 52;
        dl[0] = mx; dl[1] = ls;
#pragma unroll
        for (int dt = 0; dt < 3; dt++)
#pragma unroll
            for (int r = 0; r < 16; r++) dl[2 + dt * 16 + r] = acc[dt][r];
    }
    __syncthreads();
    if (half == 0) {
        const float* dl = dump + lane * 52;
        float mb = dl[0], lsb = dl[1];
        float mf = fmaxf(mx, mb);
        float ca = exp2f(mx - mf), cb = exp2f(mb - mf);
        float inv = 1.f / (ls * ca + lsb * cb);
        const long orow = (long)(b * TQ + q0 + q31) * DM + h * 96;
#pragma unroll
        for (int dt = 0; dt < 3; dt++)
#pragma unroll
            for (int jq = 0; jq < 4; jq++) {
                f16x4 ov;
#pragma unroll
                for (int e = 0; e < 4; e++) {
                    int r = jq * 4 + e;
                    ov[e] = (f16)((acc[dt][r] * ca + dl[2 + dt * 16 + r] * cb) * inv);
                }
                *(f16x4*)&O[orow + dt * 32 + jq * 8 + hf * 4] = ov;
            }
    }
}

// ---------------- host ----------------
extern "C" void kernel_launch(void* const* d_in, const int* in_sizes, int n_in,
                              void* d_out, int out_size, void* d_ws, size_t ws_size,
                              hipStream_t stream) {
    const float* x   = (const float*)d_in[0];
    const float* mem = (const float*)d_in[1];
    const float* qc  = (const float*)d_in[2];
    const float* mc  = (const float*)d_in[3];
    const float* Wq  = (const float*)d_in[4];
    const float* bq  = (const float*)d_in[5];
    const float* Wk  = (const float*)d_in[6];
    const float* bk  = (const float*)d_in[7];
    const float* Wv  = (const float*)d_in[8];
    const float* bv  = (const float*)d_in[9];
    const float* Wo  = (const float*)d_in[10];
    const float* bo  = (const float*)d_in[11];
    float* out = (float*)d_out;

    const long nx  = (long)NB * TQ * DM;
    const long nm  = (long)NB * TK * DM;
    const long nw  = (long)DM * DM;
    const long nq  = (long)NB * NH * TQ * 96;
    const long nkp = (long)NB * NH * TK * 128;
    const long nvt = (long)NB * NH * HD * TK;

    char* ws = (char*)d_ws;
    size_t off = 0;
    auto alloc = [&](size_t bytes) { size_t o = off; off = (off + bytes + 255) & ~(size_t)255; return o; };
    f16* x16   = (f16*)(ws + alloc(nx * 2));     // reused as at16 after Q-proj
    f16* mem16 = (f16*)(ws + alloc(nm * 2));
    f16* wq16  = (f16*)(ws + alloc(nw * 2));
    f16* wk16  = (f16*)(ws + alloc(nw * 2));
    f16* wv16  = (f16*)(ws + alloc(nw * 2));
    f16* wo16  = (f16*)(ws + alloc(nw * 2));
    f16* q16   = (f16*)(ws + alloc(nq * 2));
    f16* k16p  = (f16*)(ws + alloc(nkp * 2));
    f16* vt16  = (f16*)(ws + alloc(nvt * 2));
    float* sinq = (float*)(ws + alloc((size_t)NB * TQ * 48 * 4));
    float* cosq = (float*)(ws + alloc((size_t)NB * TQ * 48 * 4));
    float* sink = (float*)(ws + alloc((size_t)NB * TK * 48 * 4));
    float* cosk = (float*)(ws + alloc((size_t)NB * TK * 48 * 4));
    f16* at16 = x16;

    cvt_w4<<<dim3((int)(nw / 4 / 256), 4), 256, 0, stream>>>(
        (const float4*)Wq, (const float4*)Wk, (const float4*)Wv, (const float4*)Wo,
        (f16x4*)wq16, (f16x4*)wk16, (f16x4*)wv16, (f16x4*)wo16, (int)(nw / 4));
    cvt_xm<<<dim3((int)(nm / 4 / 256), 2), 256, 0, stream>>>(
        (const float4*)x, (const float4*)mem, (f16x4*)x16, (f16x4*)mem16,
        (int)(nx / 4), (int)(nm / 4));

    rope_tab2<<<dim3((NB * TK * 48 + 255) / 256, 2), 256, 0, stream>>>(
        qc, mc, sinq, cosq, sink, cosk, NB * TQ * 48, NB * TK * 48);

    // fused QKV projection: 240 blocks (48 Q + 96 K + 96 V), one dispatch round
    gemmP<0><<<240, 512, 0, stream>>>(
        x16, mem16, wq16, wk16, wv16, bq, bk, bv, q16, k16p, vt16, nullptr);

    const float qscale = 0.10206207261596577f * 1.4426950408889634f;  // 1/sqrt(96)*log2(e)
    rope_apply_k<<<(NB * NH * TQ * 48 + 255) / 256, 256, 0, stream>>>(
        q16, sinq, cosq, TQ, 96, qscale, NB * NH * TQ * 48);
    rope_apply_k<<<(NB * NH * TK * 48 + 255) / 256, 256, 0, stream>>>(
        k16p, sink, cosk, TK, 128, 1.0f, NB * NH * TK * 48);

    attn_fwd<<<dim3(16, 16, 2), 256, 0, stream>>>(q16, k16p, vt16, at16);

    // output projection -> f32 (128x128 tiles, 192 blocks, 2 blocks/CU)
    gemmP<1><<<192, 256, 0, stream>>>(
        at16, nullptr, wo16, nullptr, nullptr, bo, nullptr, nullptr,
        nullptr, nullptr, nullptr, out);
}

// Round 11
// 155.791 us; speedup vs baseline: 1.0612x; 1.0556x over previous
//
#include <hip/hip_runtime.h>
#include <math.h>

typedef _Float16 f16;
typedef __attribute__((ext_vector_type(4))) _Float16 f16x4;
typedef __attribute__((ext_vector_type(8))) _Float16 f16x8;
typedef __attribute__((ext_vector_type(4))) float f32x4;
typedef __attribute__((ext_vector_type(16))) float f32x16;

#define NB 2
#define NH 16
#define TQ 1024
#define TK 2048
#define DM 1536
#define HD 96
#define RH 48

__device__ __forceinline__ f32x4 mfma16(f16x8 a, f16x8 b, f32x4 c) {
    return __builtin_amdgcn_mfma_f32_16x16x32_f16(a, b, c, 0, 0, 0);
}

#define GLDS16(gptr, lptr) __builtin_amdgcn_global_load_lds( \
    (const __attribute__((address_space(1))) unsigned int*)(gptr), \
    (__attribute__((address_space(3))) unsigned int*)(lptr), 16, 0, 0)

// ---------------- f32 -> f16 conversion: 6 tensors, one launch ----------------
__global__ void cvt6(const float4* __restrict__ Wq, const float4* __restrict__ Wk,
                     const float4* __restrict__ Wv, const float4* __restrict__ Wo,
                     const float4* __restrict__ X,  const float4* __restrict__ M,
                     f16x4* __restrict__ oq, f16x4* __restrict__ ok,
                     f16x4* __restrict__ ov, f16x4* __restrict__ oo,
                     f16x4* __restrict__ ox, f16x4* __restrict__ om,
                     int nw4, int nx4, int nm4) {
    int i = blockIdx.x * 256 + threadIdx.x;
    const int y = blockIdx.y;
    const int n = (y < 4) ? nw4 : (y == 4 ? nx4 : nm4);
    if (i >= n) return;
    const float4* in = y == 0 ? Wq : y == 1 ? Wk : y == 2 ? Wv : y == 3 ? Wo : y == 4 ? X : M;
    f16x4* out      = y == 0 ? oq : y == 1 ? ok : y == 2 ? ov : y == 3 ? oo : y == 4 ? ox : om;
    float4 v = in[i];
    f16x4 o;
    o[0] = (f16)v.x; o[1] = (f16)v.y; o[2] = (f16)v.z; o[3] = (f16)v.w;
    out[i] = o;
}

// ---------------- RoPE sin/cos tables: [B*T][48] ----------------
__global__ void rope_tab2(const float* __restrict__ cq, const float* __restrict__ cm,
                          float* __restrict__ sq, float* __restrict__ cqo,
                          float* __restrict__ sk, float* __restrict__ cko,
                          int nq, int nk) {
    int i = blockIdx.x * 256 + threadIdx.x;
    int n = blockIdx.y == 0 ? nq : nk;
    if (i >= n) return;
    const float* coords = blockIdx.y == 0 ? cq : cm;
    float* sinT = blockIdx.y == 0 ? sq : sk;
    float* cosT = blockIdx.y == 0 ? cqo : cko;
    int bt = i / 48, idx = i - bt * 48;
    int axis = idx >> 4, f = idx & 15;
    float inv = powf(10000.f, -(float)f * (1.f / 16.f));
    float ang = coords[bt * 3 + axis] * inv;
    sinT[i] = sinf(ang);
    cosT[i] = cosf(ang);
}

// ---------------- K RoPE, vectorized: thread = (row, 4-pair group) ----------------
// K padded [B,H,TK,128]; pairs (p, p+48), p = j*4.. j in [0,12)
__global__ void ropek4(f16* __restrict__ qk, const float* __restrict__ sinT,
                       const float* __restrict__ cosT, int n) {
    int i = blockIdx.x * 256 + threadIdx.x;
    if (i >= n) return;
    int j = i % 12, row = i / 12;            // row = (b*NH+h)*TK + t
    int p0 = j * 4;
    int t = row & (TK - 1);
    int b = row / (NH * TK);
    long base = (long)row * 128;
    float4 sv = *(const float4*)&sinT[((long)b * TK + t) * 48 + p0];
    float4 cv = *(const float4*)&cosT[((long)b * TK + t) * 48 + p0];
    f16x4 x1 = *(const f16x4*)&qk[base + p0];
    f16x4 x2 = *(const f16x4*)&qk[base + p0 + RH];
    f16x4 o1, o2;
    float s[4] = {sv.x, sv.y, sv.z, sv.w}, c[4] = {cv.x, cv.y, cv.z, cv.w};
#pragma unroll
    for (int e = 0; e < 4; e++) {
        float a = (float)x1[e], bb = (float)x2[e];
        o1[e] = (f16)(a * c[e] - bb * s[e]);
        o2[e] = (f16)(bb * c[e] + a * s[e]);
    }
    *(f16x4*)&qk[base + p0] = o1;
    *(f16x4*)&qk[base + p0 + RH] = o2;
}

// ---------------- GEMM (round-7 proven: 61us, 0 conflicts) ----------------
// CFG 0: fused QKV. BM=BN=256, 512 thr (8 waves 2Mx4N, wave tile 128x64), grid 240.
// CFG 1: O-proj. BM=BN=128, 256 thr (4 waves 2x2), grid 192, f32 out.
// 2 LDS buffers; STAGE(t+1); vmcnt(8); barrier; COMPUTE(t); barrier.
// LDS rows 128B, seg^(row&7) swizzle via pre-swizzled global source.
template <int CFG>
__global__ __launch_bounds__(CFG == 0 ? 512 : 256, CFG == 0 ? 1 : 2)
void gemmP(const f16* __restrict__ Aq, const f16* __restrict__ Akv,
           const f16* __restrict__ Wqp, const f16* __restrict__ Wkp, const f16* __restrict__ Wvp,
           const float* __restrict__ bqp, const float* __restrict__ bkp, const float* __restrict__ bvp,
           f16* __restrict__ outq, f16* __restrict__ outk, f16* __restrict__ outv,
           float* __restrict__ outo) {
    constexpr int BMx = CFG == 0 ? 256 : 128;
    constexpr int BNx = CFG == 0 ? 256 : 128;
    constexpr int TPB = CFG == 0 ? 512 : 256;
    constexpr int MI  = CFG == 0 ? 8 : 4;
    constexpr int NI  = 4;
    constexpr int ABUF = BMx * 64;
    constexpr int BUFSZ = (BMx + BNx) * 64;
    constexpr int NT = DM / 64;               // 24 K-tiles

    __shared__ f16 Buf[2][BUFSZ];

    const int tid = threadIdx.x, w = tid >> 6, lane = tid & 63;
    const int l15 = lane & 15, g = lane >> 4;

    int sel = 0, mt, nt;
    const f16* A; const f16* W; const float* bias;
    if constexpr (CFG == 0) {
        const int bid = blockIdx.x;
        const int wid = (bid & 7) * 30 + (bid >> 3);   // bijective (240 = 8*30)
        if (wid < 48)       { sel = 0; mt = wid / 6;        nt = wid - mt * 6;        A = Aq;  W = Wqp; bias = bqp; }
        else if (wid < 144) { sel = 1; int r = wid - 48;  mt = r / 6; nt = r - mt * 6; A = Akv; W = Wkp; bias = bkp; }
        else                { sel = 2; int r = wid - 144; mt = r / 6; nt = r - mt * 6; A = Akv; W = Wvp; bias = bvp; }
    } else {
        const int bid = blockIdx.x;
        const int wid = (bid & 7) * 24 + (bid >> 3);   // bijective (192 = 8*24)
        mt = wid / 12; nt = wid - mt * 12;
        A = Aq; W = Wqp; bias = bqp;
    }
    const int m0 = mt * BMx, n0 = nt * BNx;
    const int wm = (w & 1) * (MI * 16);
    const int wn = (w >> 1) * 64;

    int src[4];
#pragma unroll
    for (int r = 0; r < 4; r++) {
        int L = r * (TPB * 16) + tid * 16;
        int row = L >> 7, seg = (L >> 4) & 7;
        src[r] = row * DM + ((seg ^ (row & 7)) << 3);
    }
    const f16* Ag = A + (long)m0 * DM;
    const f16* Bg = W + (long)n0 * DM;

    int aoff[MI][2], boff[NI][2];
#pragma unroll
    for (int i = 0; i < MI; i++) {
        int row = wm + i * 16 + l15;
#pragma unroll
        for (int s = 0; s < 2; s++)
            aoff[i][s] = row * 64 + (((s * 4 + g) ^ (row & 7)) << 3);
    }
#pragma unroll
    for (int j = 0; j < NI; j++) {
        int row = wn + j * 16 + l15;
#pragma unroll
        for (int s = 0; s < 2; s++)
            boff[j][s] = ABUF + row * 64 + (((s * 4 + g) ^ (row & 7)) << 3);
    }

#define STG(bufp, kt) do { \
    _Pragma("unroll") for (int r_ = 0; r_ < 4; r_++) { \
        GLDS16(Ag + src[r_] + (kt) * 64, &Buf[bufp][r_ * (TPB * 8) + w * 512]); \
        GLDS16(Bg + src[r_] + (kt) * 64, &Buf[bufp][ABUF + r_ * (TPB * 8) + w * 512]); \
    } \
} while (0)

    f32x4 acc[MI][NI] = {};

#define COMPUTE(bufp) do { \
    f16x8 bf[NI][2]; \
    _Pragma("unroll") for (int j_ = 0; j_ < NI; j_++) \
        _Pragma("unroll") for (int s_ = 0; s_ < 2; s_++) \
            bf[j_][s_] = *(const f16x8*)&Buf[bufp][boff[j_][s_]]; \
    __builtin_amdgcn_s_setprio(1); \
    _Pragma("unroll") for (int i_ = 0; i_ < MI; i_++) { \
        f16x8 a0 = *(const f16x8*)&Buf[bufp][aoff[i_][0]]; \
        f16x8 a1 = *(const f16x8*)&Buf[bufp][aoff[i_][1]]; \
        _Pragma("unroll") for (int j_ = 0; j_ < NI; j_++) { \
            acc[i_][j_] = mfma16(a0, bf[j_][0], acc[i_][j_]); \
            acc[i_][j_] = mfma16(a1, bf[j_][1], acc[i_][j_]); \
        } \
    } \
    __builtin_amdgcn_s_setprio(0); \
} while (0)

    STG(0, 0);
#pragma unroll 1
    for (int t = 0; t < NT; t += 2) {
        STG(1, t + 1);
        asm volatile("s_waitcnt vmcnt(8)" ::: "memory");
        __builtin_amdgcn_s_barrier();
        __builtin_amdgcn_sched_barrier(0);
        COMPUTE(0);
        __builtin_amdgcn_sched_barrier(0);
        __builtin_amdgcn_s_barrier();
        if (t + 2 < NT) {
            STG(0, t + 2);
            asm volatile("s_waitcnt vmcnt(8)" ::: "memory");
        } else {
            asm volatile("s_waitcnt vmcnt(0)" ::: "memory");
        }
        __builtin_amdgcn_s_barrier();
        __builtin_amdgcn_sched_barrier(0);
        COMPUTE(1);
        __builtin_amdgcn_sched_barrier(0);
        __builtin_amdgcn_s_barrier();
    }
#undef STG
#undef COMPUTE

    // ---- epilogue ----
#pragma unroll
    for (int i = 0; i < MI; i++) {
#pragma unroll
        for (int j = 0; j < NI; j++) {
            const int n = n0 + wn + j * 16 + l15;
            const int mb = m0 + wm + i * 16 + g * 4;
            if constexpr (CFG == 1) {
#pragma unroll
                for (int r = 0; r < 4; r++)
                    outo[(long)(mb + r) * DM + n] = acc[i][j][r] + bias[n];
            } else {
                const int hh = n / HD, hd = n - hh * HD;
                if (sel == 0) {            // Q [B,H,TQ,96] (raw: rope applied in attn)
#pragma unroll
                    for (int r = 0; r < 4; r++) {
                        int m = mb + r, bq = m >> 10, t = m & (TQ - 1);
                        outq[(((long)bq * NH + hh) * TQ + t) * 96 + hd] = (f16)(acc[i][j][r] + bias[n]);
                    }
                } else if (sel == 1) {     // K padded [B,H,TK,128]
#pragma unroll
                    for (int r = 0; r < 4; r++) {
                        int m = mb + r, bq = m >> 11, t = m & (TK - 1);
                        outk[(((long)bq * NH + hh) * TK + t) * 128 + hd] = (f16)(acc[i][j][r] + bias[n]);
                    }
                } else {                   // V^T [B,H,96,TK]
                    int bq = mb >> 11, t = mb & (TK - 1);
                    f16x4 pk;
#pragma unroll
                    for (int r = 0; r < 4; r++) pk[r] = (f16)(acc[i][j][r] + bias[n]);
                    *(f16x4*)&outv[(((long)bq * NH + hh) * HD + hd) * TK + t] = pk;
                }
            }
        }
    }
}

// ---------------- Flash attention + fused Q-RoPE ----------------
// Q raw [B,H,TQ,96]; rope pairs (d,d+48) are lane-local: qf[s][e] <-> qf[s+3][e],
// table p = hf*8+16s+e. qscale*log2e folded here.
__global__ __launch_bounds__(256, 2) void attn_fwd(
    const f16* __restrict__ Q, const f16* __restrict__ Kg,
    const f16* __restrict__ Vg, const float* __restrict__ sinq,
    const float* __restrict__ cosq, f16* __restrict__ O) {
    __shared__ f16 Kl[2][64 * 128];
    __shared__ f16 Vl[2][96 * 64];
    __shared__ f16 Pl[4][32 * 64];

    const int tid = threadIdx.x, w = tid >> 6, lane = tid & 63;
    const int q31 = lane & 31, hf = lane >> 5;
    const int half = w >> 1, u = w & 1;

    const int linear = blockIdx.x + (int)(gridDim.x * (blockIdx.y + gridDim.y * blockIdx.z));
    const int wid = (linear & 7) * 64 + (linear >> 3);
    const int qc = wid & 15, h = (wid >> 4) & 15, b = wid >> 8;

    const long kbase = (long)(b * NH + h) * TK * 128;
    const long vbase = (long)(b * NH + h) * HD * TK;
    const long qbase = (long)(b * NH + h) * TQ * 96;
    const int q0 = qc * 64 + u * 32;

    int ksrc[8], vsrc[6];
#pragma unroll
    for (int i = 0; i < 8; i++) {
        int L = (u * 8 + i) * 1024 + lane * 16;
        int r = L >> 8, s = (L >> 4) & 15;
        ksrc[i] = r * 128 + ((s ^ (r & 7)) << 3);
    }
#pragma unroll
    for (int i = 0; i < 6; i++) {
        int L = (u * 6 + i) * 1024 + lane * 16;
        int r = L >> 7, s = (L >> 4) & 7;
        vsrc[i] = r * TK + ((s ^ (r & 7)) << 3);
    }

    // ---- Q fragments + in-register RoPE + scale ----
    f16x8 qf[6];
#pragma unroll
    for (int s = 0; s < 6; s++)
        qf[s] = *(const f16x8*)&Q[qbase + (long)(q0 + q31) * 96 + hf * 8 + 16 * s];
    {
        const float QS = 0.10206207261596577f * 1.4426950408889634f;  // 1/sqrt(96)*log2(e)
        const long tb = ((long)b * TQ + q0 + q31) * 48 + hf * 8;
#pragma unroll
        for (int s = 0; s < 3; s++) {
            float4 s0 = *(const float4*)&sinq[tb + 16 * s];
            float4 s1 = *(const float4*)&sinq[tb + 16 * s + 4];
            float4 c0 = *(const float4*)&cosq[tb + 16 * s];
            float4 c1 = *(const float4*)&cosq[tb + 16 * s + 4];
            float sv[8] = {s0.x, s0.y, s0.z, s0.w, s1.x, s1.y, s1.z, s1.w};
            float cv[8] = {c0.x, c0.y, c0.z, c0.w, c1.x, c1.y, c1.z, c1.w};
#pragma unroll
            for (int e = 0; e < 8; e++) {
                float x1 = (float)qf[s][e], x2 = (float)qf[s + 3][e];
                qf[s][e]     = (f16)((x1 * cv[e] - x2 * sv[e]) * QS);
                qf[s + 3][e] = (f16)((x2 * cv[e] + x1 * sv[e]) * QS);
            }
        }
    }

    float mx = -3e38f, ls = 0.f;
    f32x16 acc[3] = {};

#define STAGE(c_) do { \
    const f16* kp_ = Kg + kbase + (long)(half * 16 + (c_)) * (64 * 128); \
    _Pragma("unroll") for (int i_ = 0; i_ < 8; i_++) \
        GLDS16(kp_ + ksrc[i_], &Kl[half][(u * 8 + i_) * 512]); \
    const f16* vp_ = Vg + vbase + (half * 16 + (c_)) * 64; \
    _Pragma("unroll") for (int i_ = 0; i_ < 6; i_++) \
        GLDS16(vp_ + vsrc[i_], &Vl[half][(u * 6 + i_) * 512]); \
} while (0)

    STAGE(0);

    for (int c = 0; c < 16; ++c) {
        __syncthreads();

        f32x16 st[2] = {};
#pragma unroll
        for (int kt = 0; kt < 2; kt++)
#pragma unroll
            for (int s = 0; s < 6; s++) {
                f16x8 kf = *(const f16x8*)&Kl[half][(kt * 32 + q31) * 128 +
                                                    (((hf + 2 * s) ^ (q31 & 7)) << 3)];
                st[kt] = __builtin_amdgcn_mfma_f32_32x32x16_f16(kf, qf[s], st[kt], 0, 0, 0);
            }

        float t16[16];
#pragma unroll
        for (int r = 0; r < 16; r++) t16[r] = fmaxf(st[0][r], st[1][r]);
#pragma unroll
        for (int o = 8; o >= 1; o >>= 1)
#pragma unroll
            for (int r = 0; r < o; r++) t16[r] = fmaxf(t16[r], t16[r + o]);
        float cm = fmaxf(t16[0], __shfl_xor(t16[0], 32));
        float mn = fmaxf(mx, cm);
        float corr = exp2f(mx - mn);
        mx = mn;
#pragma unroll
        for (int kt = 0; kt < 2; kt++)
#pragma unroll
            for (int r = 0; r < 16; r++) st[kt][r] = exp2f(st[kt][r] - mn);
        float s16[16];
#pragma unroll
        for (int r = 0; r < 16; r++) s16[r] = st[0][r] + st[1][r];
#pragma unroll
        for (int o = 8; o >= 1; o >>= 1)
#pragma unroll
            for (int r = 0; r < o; r++) s16[r] += s16[r + o];
        ls = ls * corr + s16[0];
#pragma unroll
        for (int dt = 0; dt < 3; dt++)
#pragma unroll
            for (int r = 0; r < 16; r++) acc[dt][r] *= corr;

#pragma unroll
        for (int kt = 0; kt < 2; kt++)
#pragma unroll
            for (int jq = 0; jq < 4; jq++) {
                f16x4 pk;
#pragma unroll
                for (int e = 0; e < 4; e++) pk[e] = (f16)st[kt][jq * 4 + e];
                int seg = kt * 4 + jq;
                *(f16x4*)&Pl[w][q31 * 64 + ((seg ^ (q31 & 7)) << 3) + hf * 4] = pk;
            }

#pragma unroll
        for (int ks = 0; ks < 4; ks++) {
            f16x8 pf = *(const f16x8*)&Pl[w][q31 * 64 + (((hf + 2 * ks) ^ (q31 & 7)) << 3)];
#pragma unroll
            for (int dt = 0; dt < 3; dt++) {
                f16x8 vf = *(const f16x8*)&Vl[half][(dt * 32 + q31) * 64 +
                                                    (((hf + 2 * ks) ^ (q31 & 7)) << 3)];
                acc[dt] = __builtin_amdgcn_mfma_f32_32x32x16_f16(vf, pf, acc[dt], 0, 0, 0);
            }
        }

        __syncthreads();
        if (c < 15) STAGE(c + 1);
    }

    ls += __shfl_xor(ls, 32);
    float* dump = (float*)&Kl[0][0] + u * (64 * 52);
    __syncthreads();
    if (half == 1) {
        float* dl = dump + lane * 52;
        dl[0] = mx; dl[1] = ls;
#pragma unroll
        for (int dt = 0; dt < 3; dt++)
#pragma unroll
            for (int r = 0; r < 16; r++) dl[2 + dt * 16 + r] = acc[dt][r];
    }
    __syncthreads();
    if (half == 0) {
        const float* dl = dump + lane * 52;
        float mb = dl[0], lsb = dl[1];
        float mf = fmaxf(mx, mb);
        float ca = exp2f(mx - mf), cb = exp2f(mb - mf);
        float inv = 1.f / (ls * ca + lsb * cb);
        const long orow = (long)(b * TQ + q0 + q31) * DM + h * 96;
#pragma unroll
        for (int dt = 0; dt < 3; dt++)
#pragma unroll
            for (int jq = 0; jq < 4; jq++) {
                f16x4 ov;
#pragma unroll
                for (int e = 0; e < 4; e++) {
                    int r = jq * 4 + e;
                    ov[e] = (f16)((acc[dt][r] * ca + dl[2 + dt * 16 + r] * cb) * inv);
                }
                *(f16x4*)&O[orow + dt * 32 + jq * 8 + hf * 4] = ov;
            }
    }
}

// ---------------- host ----------------
extern "C" void kernel_launch(void* const* d_in, const int* in_sizes, int n_in,
                              void* d_out, int out_size, void* d_ws, size_t ws_size,
                              hipStream_t stream) {
    const float* x   = (const float*)d_in[0];
    const float* mem = (const float*)d_in[1];
    const float* qc  = (const float*)d_in[2];
    const float* mc  = (const float*)d_in[3];
    const float* Wq  = (const float*)d_in[4];
    const float* bq  = (const float*)d_in[5];
    const float* Wk  = (const float*)d_in[6];
    const float* bk  = (const float*)d_in[7];
    const float* Wv  = (const float*)d_in[8];
    const float* bv  = (const float*)d_in[9];
    const float* Wo  = (const float*)d_in[10];
    const float* bo  = (const float*)d_in[11];
    float* out = (float*)d_out;

    const long nx  = (long)NB * TQ * DM;
    const long nm  = (long)NB * TK * DM;
    const long nw  = (long)DM * DM;
    const long nq  = (long)NB * NH * TQ * 96;
    const long nkp = (long)NB * NH * TK * 128;
    const long nvt = (long)NB * NH * HD * TK;

    char* ws = (char*)d_ws;
    size_t off = 0;
    auto alloc = [&](size_t bytes) { size_t o = off; off = (off + bytes + 255) & ~(size_t)255; return o; };
    f16* x16   = (f16*)(ws + alloc(nx * 2));     // reused as at16 after Q-proj
    f16* mem16 = (f16*)(ws + alloc(nm * 2));
    f16* wq16  = (f16*)(ws + alloc(nw * 2));
    f16* wk16  = (f16*)(ws + alloc(nw * 2));
    f16* wv16  = (f16*)(ws + alloc(nw * 2));
    f16* wo16  = (f16*)(ws + alloc(nw * 2));
    f16* q16   = (f16*)(ws + alloc(nq * 2));
    f16* k16p  = (f16*)(ws + alloc(nkp * 2));
    f16* vt16  = (f16*)(ws + alloc(nvt * 2));
    float* sinq = (float*)(ws + alloc((size_t)NB * TQ * 48 * 4));
    float* cosq = (float*)(ws + alloc((size_t)NB * TQ * 48 * 4));
    float* sink = (float*)(ws + alloc((size_t)NB * TK * 48 * 4));
    float* cosk = (float*)(ws + alloc((size_t)NB * TK * 48 * 4));
    f16* at16 = x16;

    // conversions: one launch (6 tensors)
    cvt6<<<dim3((int)(nm / 4 / 256), 6), 256, 0, stream>>>(
        (const float4*)Wq, (const float4*)Wk, (const float4*)Wv, (const float4*)Wo,
        (const float4*)x, (const float4*)mem,
        (f16x4*)wq16, (f16x4*)wk16, (f16x4*)wv16, (f16x4*)wo16,
        (f16x4*)x16, (f16x4*)mem16,
        (int)(nw / 4), (int)(nx / 4), (int)(nm / 4));

    rope_tab2<<<dim3((NB * TK * 48 + 255) / 256, 2), 256, 0, stream>>>(
        qc, mc, sinq, cosq, sink, cosk, NB * TQ * 48, NB * TK * 48);

    // fused QKV projection: 240 blocks (48 Q + 96 K + 96 V)
    gemmP<0><<<240, 512, 0, stream>>>(
        x16, mem16, wq16, wk16, wv16, bq, bk, bv, q16, k16p, vt16, nullptr);

    // K rope (vectorized); Q rope fused into attention
    ropek4<<<(NB * NH * TK * 12 + 255) / 256, 256, 0, stream>>>(
        k16p, sink, cosk, NB * NH * TK * 12);

    attn_fwd<<<dim3(16, 16, 2), 256, 0, stream>>>(q16, k16p, vt16, sinq, cosq, at16);

    // output projection -> f32 (128x128 tiles, 192 blocks, 2 blocks/CU)
    gemmP<1><<<192, 256, 0, stream>>>(
        at16, nullptr, wo16, nullptr, nullptr, bo, nullptr, nullptr,
        nullptr, nullptr, nullptr, out);
}